// Round 15
// baseline (141.577 us; speedup 1.0000x reference)
//
#include <hip/hip_runtime.h>
#include <math.h>

#define Bb 4
#define Cc 192
#define NN 1024
#define HD 384
#define NH 4
#define FF 1536   // NH*HD
#define KN 16
#define BN_EPS 1e-5f

typedef __attribute__((ext_vector_type(8))) short bf16x8;
typedef __attribute__((ext_vector_type(4))) float f32x4;

__device__ inline float b2f(ushort u) {
  return __uint_as_float(((unsigned)u) << 16);
}
__device__ inline ushort f2b(float f) {
  unsigned v = __float_as_uint(f);
  return (ushort)((v + 0x7fffu + ((v >> 16) & 1u)) >> 16);
}

// one row of register-tile FMAs: acc.{x,y,z,w} += av * b.{x,y,z,w}
#define FMA_ROW(ACC, AV, B) \
  ACC.x = fmaf(AV, B.x, ACC.x); ACC.y = fmaf(AV, B.y, ACC.y); \
  ACC.z = fmaf(AV, B.z, ACC.z); ACC.w = fmaf(AV, B.w, ACC.w);

// ---------------------------------------------------------------- prep:
// W1T fp32 transpose (36), W2b bf16 convert (72), WgTb bf16 transpose (288),
// Asml[k][j] = dot(Wg[k, h*HD:], att) folded attention (6). Total 402 blocks.
__global__ __launch_bounds__(256) void k_prep(
    const float* __restrict__ W1, const float* __restrict__ W2,
    const float* __restrict__ Wg, const float* __restrict__ att_src,
    const float* __restrict__ att_dst, float* __restrict__ W1T,
    ushort* __restrict__ W2b, ushort* __restrict__ WgTb,
    float* __restrict__ Asml) {
  __shared__ float tile[32][33];
  int id = blockIdx.x;
  int t = threadIdx.x;
  if (id < 36 || (id >= 108 && id < 396)) {
    const float* in; int R, C, cx, cy;
    float* outf = nullptr; ushort* outb = nullptr;
    if (id < 36) { in = W1; R = Cc; C = Cc; cx = id % 6; cy = id / 6; outf = W1T; }
    else { int q = id - 108; in = Wg; R = Cc; C = FF; cx = q % 48; cy = q / 48; outb = WgTb; }
    int c0 = cx * 32, r0 = cy * 32;
    int tx = t & 31, ty = t >> 5;
#pragma unroll
    for (int i = 0; i < 4; ++i) {
      int r = ty + i * 8;
      tile[r][tx] = in[(size_t)(r0 + r) * C + c0 + tx];
    }
    __syncthreads();
#pragma unroll
    for (int i = 0; i < 4; ++i) {
      int r = ty + i * 8;
      float v = tile[tx][r];
      if (outf) outf[(size_t)(c0 + r) * R + r0 + tx] = v;
      else      outb[(size_t)(c0 + r) * R + r0 + tx] = f2b(v);
    }
  } else if (id < 108) {               // W2 bf16 convert (row-major kept)
    int base = (id - 36) * 1024 + t * 4;
    float4 v = *(const float4*)&W2[base];
    ushort4 o = {f2b(v.x), f2b(v.y), f2b(v.z), f2b(v.w)};
    *(ushort4*)&W2b[base] = o;
  } else {                             // Asml: j<4 -> src, j>=4 -> dst
    int gi = (id - 396) * 256 + t;     // 0..1535
    int k = gi >> 3, j = gi & 7;
    int h = j & 3;
    const float* av = (j < 4) ? att_src : att_dst;
    float acc = 0.f;
    for (int d = 0; d < HD; ++d)
      acc = fmaf(Wg[(size_t)k * FF + h * HD + d], av[h * HD + d], acc);
    Asml[k * 8 + j] = acc;
  }
}

// ---------------------------------------------------------------- fc1 + BN (bit-frozen; emits y fp32, yb bf16, yT fp32)
__global__ __launch_bounds__(256) void k_fc1(
    const float* __restrict__ x, const float* __restrict__ W1T,
    const float* __restrict__ b1, const float* __restrict__ bn1,
    float* __restrict__ y, ushort* __restrict__ yb,
    float* __restrict__ yT) {
  int nt = blockIdx.x, ct = blockIdx.y, b = blockIdx.z;
  int n0 = nt * 64, ct64 = ct * 64;
  __shared__ float As[64][64];
  __shared__ float Bs[64][64];
  __shared__ float ctile[64][68];   // [c][n], 68 stride: 16B-aligned rows
  int t = threadIdx.x;
  int tx = t & 15, ty = t >> 4;
  float4 acc[4];
#pragma unroll
  for (int i = 0; i < 4; ++i) acc[i] = {0.f, 0.f, 0.f, 0.f};
  for (int k0 = 0; k0 < Cc; k0 += 64) {
    __syncthreads();
#pragma unroll
    for (int i = 0; i < 4; ++i) {
      int fi = i * 256 + t;
      int r = fi >> 4, q = fi & 15;
      *(float4*)&As[r][q * 4] =
          *(const float4*)&x[((size_t)b * Cc + k0 + r) * NN + n0 + q * 4];
      *(float4*)&Bs[r][q * 4] =
          *(const float4*)&W1T[(size_t)(k0 + r) * Cc + ct64 + q * 4];
    }
    __syncthreads();
#pragma unroll 8
    for (int k = 0; k < 64; ++k) {
      float4 a = *(const float4*)&As[k][ty * 4];
      float4 bv = *(const float4*)&Bs[k][tx * 4];
      FMA_ROW(acc[0], a.x, bv)
      FMA_ROW(acc[1], a.y, bv)
      FMA_ROW(acc[2], a.z, bv)
      FMA_ROW(acc[3], a.w, bv)
    }
  }
  float s[4], mm[4], be[4], bias[4];
#pragma unroll
  for (int jj = 0; jj < 4; ++jj) {
    int c = ct64 + tx * 4 + jj;
    s[jj]    = bn1[c] / sqrtf(bn1[3 * Cc + c] + BN_EPS);
    mm[jj]   = bn1[2 * Cc + c];
    be[jj]   = bn1[Cc + c];
    bias[jj] = b1[c];
  }
  float accm[4][4] = {
      {acc[0].x, acc[0].y, acc[0].z, acc[0].w},
      {acc[1].x, acc[1].y, acc[1].z, acc[1].w},
      {acc[2].x, acc[2].y, acc[2].z, acc[2].w},
      {acc[3].x, acc[3].y, acc[3].z, acc[3].w}};
#pragma unroll
  for (int ii = 0; ii < 4; ++ii) {
    int n = n0 + ty * 4 + ii;
    float4 o;
    o.x = (accm[ii][0] + bias[0] - mm[0]) * s[0] + be[0];
    o.y = (accm[ii][1] + bias[1] - mm[1]) * s[1] + be[1];
    o.z = (accm[ii][2] + bias[2] - mm[2]) * s[2] + be[2];
    o.w = (accm[ii][3] + bias[3] - mm[3]) * s[3] + be[3];
    *(float4*)&y[((size_t)b * NN + n) * Cc + ct64 + tx * 4] = o;
    ushort4 ob = {f2b(o.x), f2b(o.y), f2b(o.z), f2b(o.w)};
    *(ushort4*)&yb[((size_t)b * NN + n) * Cc + ct64 + tx * 4] = ob;
    ctile[tx * 4 + 0][ty * 4 + ii] = o.x;
    ctile[tx * 4 + 1][ty * 4 + ii] = o.y;
    ctile[tx * 4 + 2][ty * 4 + ii] = o.z;
    ctile[tx * 4 + 3][ty * 4 + ii] = o.w;
  }
  __syncthreads();
#pragma unroll
  for (int i = 0; i < 4; ++i) {        // 64 c-rows x 16 float4 n-units
    int u = i * 256 + t;
    int cl = u >> 4, q = u & 15;
    float4 v = *(const float4*)&ctile[cl][q * 4];
    *(float4*)&yT[((size_t)b * Cc + ct64 + cl) * NN + n0 + q * 4] = v;
  }
}

// ---------------------------------------------------------------- sq (bit-frozen chain) + folded attn coefs, one pass over y
// sq: identical loads, fmaf chain, and __shfl_down cascade as the old k_sq
// -> bit-identical sq. asrc/adst: y @ Asml (smooth path; fold proven in R10).
__global__ __launch_bounds__(64) void k_sqatt(
    const float* __restrict__ y, const float* __restrict__ Asml,
    float* __restrict__ sq, float* __restrict__ asrc,
    float* __restrict__ adst) {
  int bn = blockIdx.x;
  int lane = threadIdx.x;
  const float* yp = y + (size_t)bn * Cc;
  float s = 0.f;
  float p[8] = {0.f, 0.f, 0.f, 0.f, 0.f, 0.f, 0.f, 0.f};
#pragma unroll
  for (int i = 0; i < 3; ++i) {
    int k = lane + i * 64;
    float v = yp[k];
    s = fmaf(v, v, s);                       // same chain as old k_sq
    float4 a0 = *(const float4*)&Asml[k * 8];
    float4 a1 = *(const float4*)&Asml[k * 8 + 4];
    p[0] = fmaf(v, a0.x, p[0]); p[1] = fmaf(v, a0.y, p[1]);
    p[2] = fmaf(v, a0.z, p[2]); p[3] = fmaf(v, a0.w, p[3]);
    p[4] = fmaf(v, a1.x, p[4]); p[5] = fmaf(v, a1.y, p[5]);
    p[6] = fmaf(v, a1.z, p[6]); p[7] = fmaf(v, a1.w, p[7]);
  }
#pragma unroll
  for (int off = 32; off; off >>= 1) {
    s += __shfl_down(s, off);                // same cascade as old k_sq
#pragma unroll
    for (int j = 0; j < 8; ++j) p[j] += __shfl_down(p[j], off);
  }
  if (lane == 0) {
    sq[bn] = s;
    float4 o1 = {p[0], p[1], p[2], p[3]};
    float4 o2 = {p[4], p[5], p[6], p[7]};
    *(float4*)&asrc[bn * NH] = o1;
    *(float4*)&adst[bn * NH] = o2;
  }
}

// ---------------------------------------------------------------- h = y @ Wg via bf16 MFMA -> hb
__global__ __launch_bounds__(256) void k_hgemm_mfma(
    const ushort* __restrict__ yb, const ushort* __restrict__ WgTb,
    ushort* __restrict__ hb) {
  int r0 = blockIdx.x * 128, c0 = blockIdx.y * 128;
  __shared__ ushort Al[128][72];
  __shared__ ushort Bl[128][72];
  int t = threadIdx.x;
  int w = t >> 6, l = t & 63;
  int wr = w >> 1, wc = w & 1;
  f32x4 acc[4][4];
#pragma unroll
  for (int mt = 0; mt < 4; ++mt)
#pragma unroll
    for (int nt = 0; nt < 4; ++nt) acc[mt][nt] = {0.f, 0.f, 0.f, 0.f};
  for (int k0 = 0; k0 < Cc; k0 += 64) {
    __syncthreads();
#pragma unroll
    for (int i = 0; i < 4; ++i) {
      int u = i * 256 + t;
      int r = u >> 3, ko = (u & 7) * 8;
      *(int4*)&Al[r][ko] = *(const int4*)&yb[(size_t)(r0 + r) * Cc + k0 + ko];
      *(int4*)&Bl[r][ko] = *(const int4*)&WgTb[(size_t)(c0 + r) * Cc + k0 + ko];
    }
    __syncthreads();
#pragma unroll
    for (int ks = 0; ks < 2; ++ks) {
      bf16x8 af[4], bfr[4];
#pragma unroll
      for (int mt = 0; mt < 4; ++mt)
        af[mt] = *(const bf16x8*)&Al[wr * 64 + mt * 16 + (l & 15)][ks * 32 + (l >> 4) * 8];
#pragma unroll
      for (int nt = 0; nt < 4; ++nt)
        bfr[nt] = *(const bf16x8*)&Bl[wc * 64 + nt * 16 + (l & 15)][ks * 32 + (l >> 4) * 8];
#pragma unroll
      for (int mt = 0; mt < 4; ++mt)
#pragma unroll
        for (int nt = 0; nt < 4; ++nt)
          acc[mt][nt] = __builtin_amdgcn_mfma_f32_16x16x32_bf16(
              af[mt], bfr[nt], acc[mt][nt], 0, 0, 0);
    }
  }
  int col_l = l & 15, rg = l >> 4;
#pragma unroll
  for (int mt = 0; mt < 4; ++mt)
#pragma unroll
    for (int nt = 0; nt < 4; ++nt) {
      int col = c0 + wc * 64 + nt * 16 + col_l;
#pragma unroll
      for (int j = 0; j < 4; ++j) {
        int row = r0 + wr * 64 + mt * 16 + rg * 4 + j;
        hb[(size_t)row * FF + col] = f2b(acc[mt][nt][j]);
      }
    }
}

// ---------------------------------------------------------------- pairwise distances (bit-frozen; 128x64, 8x4/thread)
__global__ __launch_bounds__(256) void k_dist(const float* __restrict__ yT,
                                              const float* __restrict__ sq,
                                              float* __restrict__ dist) {
  int b = blockIdx.z;
  int n0 = blockIdx.y * 128, m0 = blockIdx.x * 64;
  __shared__ float As[64][128];
  __shared__ float Bs[64][64];
  const float* ytb = yT + (size_t)b * Cc * NN;
  int t = threadIdx.x;
  int tx = t & 15, ty = t >> 4;
  float4 acc[8];
#pragma unroll
  for (int i = 0; i < 8; ++i) acc[i] = {0.f, 0.f, 0.f, 0.f};
  for (int k0 = 0; k0 < Cc; k0 += 64) {
    __syncthreads();
#pragma unroll
    for (int i = 0; i < 8; ++i) {
      int fi = i * 256 + t;
      int kk = fi >> 5, n4 = fi & 31;
      *(float4*)&As[kk][n4 * 4] =
          *(const float4*)&ytb[(size_t)(k0 + kk) * NN + n0 + n4 * 4];
    }
#pragma unroll
    for (int i = 0; i < 4; ++i) {
      int fi = i * 256 + t;
      int kk = fi >> 4, m4 = fi & 15;
      *(float4*)&Bs[kk][m4 * 4] =
          *(const float4*)&ytb[(size_t)(k0 + kk) * NN + m0 + m4 * 4];
    }
    __syncthreads();
#pragma unroll 8
    for (int k = 0; k < 64; ++k) {
      float4 a0 = *(const float4*)&As[k][ty * 4];
      float4 a1 = *(const float4*)&As[k][64 + ty * 4];
      float4 b4 = *(const float4*)&Bs[k][tx * 4];
      FMA_ROW(acc[0], a0.x, b4)
      FMA_ROW(acc[1], a0.y, b4)
      FMA_ROW(acc[2], a0.z, b4)
      FMA_ROW(acc[3], a0.w, b4)
      FMA_ROW(acc[4], a1.x, b4)
      FMA_ROW(acc[5], a1.y, b4)
      FMA_ROW(acc[6], a1.z, b4)
      FMA_ROW(acc[7], a1.w, b4)
    }
  }
#pragma unroll
  for (int ii = 0; ii < 8; ++ii) {
    int n = n0 + ((ii < 4) ? (ty * 4 + ii) : (64 + ty * 4 + ii - 4));
    float sn = sq[b * NN + n];
    int mbase = m0 + tx * 4;
    float av[4] = {acc[ii].x, acc[ii].y, acc[ii].z, acc[ii].w};
    float4 o;
    o.x = sn + sq[b * NN + mbase + 0] - 2.f * av[0];
    o.y = sn + sq[b * NN + mbase + 1] - 2.f * av[1];
    o.z = sn + sq[b * NN + mbase + 2] - 2.f * av[2];
    o.w = sn + sq[b * NN + mbase + 3] - 2.f * av[3];
    *(float4*)&dist[((size_t)b * NN + n) * NN + mbase] = o;
  }
}

// ---------------------------------------------------------------- top-16 smallest per row (bit-frozen; single-wave)
__global__ __launch_bounds__(64) void k_topk(const float* __restrict__ dist,
                                             int* __restrict__ idx) {
  int bn = blockIdx.x;
  int lane = threadIdx.x;
  const float4* dp = (const float4*)(dist + (size_t)bn * NN);
  float dv[16];
#pragma unroll
  for (int q = 0; q < 4; ++q) {
    float4 v = dp[lane + 64 * q];
    dv[q * 4 + 0] = v.x; dv[q * 4 + 1] = v.y;
    dv[q * 4 + 2] = v.z; dv[q * 4 + 3] = v.w;
  }
  for (int sel = 0; sel < KN; ++sel) {
    float bv = INFINITY;
    int bi = 0x7fffffff;
#pragma unroll
    for (int q = 0; q < 4; ++q)
#pragma unroll
      for (int j = 0; j < 4; ++j) {
        int m = (lane + 64 * q) * 4 + j;
        float v = dv[q * 4 + j];
        if (v < bv || (v == bv && m < bi)) { bv = v; bi = m; }
      }
#pragma unroll
    for (int off = 32; off; off >>= 1) {
      float ov = __shfl_xor(bv, off);
      int oi   = __shfl_xor(bi, off);
      if (ov < bv || (ov == bv && oi < bi)) { bv = ov; bi = oi; }
    }
    if (lane == 0) idx[bn * KN + sel] = bi;
#pragma unroll
    for (int q = 0; q < 4; ++q)
#pragma unroll
      for (int j = 0; j < 4; ++j)
        if ((lane + 64 * q) * 4 + j == bi) dv[q * 4 + j] = INFINITY;
  }
}

// ---------------------------------------------------------------- GAT aggregate + BN + GELU -> gb (bf16)
__global__ __launch_bounds__(128, 4) void k_gat(
    const ushort* __restrict__ hb, const float* __restrict__ asrc,
    const float* __restrict__ adst, const int* __restrict__ idx,
    const float* __restrict__ bg, const float* __restrict__ bng,
    ushort* __restrict__ gb) {
  int bid = blockIdx.x;
  int bn = (bid & 7) * (Bb * NN / 8) + (bid >> 3);   // bijective XCD swizzle
  int b = bn / NN;
  __shared__ int nb[KN];
  __shared__ float attn[KN][NH];
  int t = threadIdx.x;
  if (t < KN) nb[t] = idx[bn * KN + t];
  __syncthreads();
  if (t < KN * NH) {
    int k = t % KN, hd = t / KN;
    float e = asrc[((size_t)b * NN + nb[k]) * NH + hd] +
              adst[(size_t)bn * NH + hd];
    e = (e >= 0.f) ? e : 0.2f * e;
    attn[k][hd] = e;
  }
  __syncthreads();
  if (t < NH) {
    float mx = -INFINITY;
    for (int k = 0; k < KN; ++k) mx = fmaxf(mx, attn[k][t]);
    float s = 0.f;
    for (int k = 0; k < KN; ++k) {
      float ev = expf(attn[k][t] - mx);
      attn[k][t] = ev;
      s += ev;
    }
    float inv = 1.f / s;
    for (int k = 0; k < KN; ++k) attn[k][t] *= inv;
  }
  __syncthreads();
  if (t < 96) {
    int d = t * 4;
    float4 acc = {0.f, 0.f, 0.f, 0.f};
#pragma unroll 4
    for (int k = 0; k < KN; ++k) {
      const ushort* hp = hb + ((size_t)b * NN + nb[k]) * FF + d;
      float4 aw = *(const float4*)&attn[k][0];
      ushort4 u0 = *(const ushort4*)&hp[0];
      ushort4 u1 = *(const ushort4*)&hp[HD];
      ushort4 u2 = *(const ushort4*)&hp[2 * HD];
      ushort4 u3 = *(const ushort4*)&hp[3 * HD];
      float4 h0 = {b2f(u0.x), b2f(u0.y), b2f(u0.z), b2f(u0.w)};
      float4 h1 = {b2f(u1.x), b2f(u1.y), b2f(u1.z), b2f(u1.w)};
      float4 h2 = {b2f(u2.x), b2f(u2.y), b2f(u2.z), b2f(u2.w)};
      float4 h3 = {b2f(u3.x), b2f(u3.y), b2f(u3.z), b2f(u3.w)};
      acc.x = fmaf(aw.x, h0.x, acc.x); acc.x = fmaf(aw.y, h1.x, acc.x);
      acc.x = fmaf(aw.z, h2.x, acc.x); acc.x = fmaf(aw.w, h3.x, acc.x);
      acc.y = fmaf(aw.x, h0.y, acc.y); acc.y = fmaf(aw.y, h1.y, acc.y);
      acc.y = fmaf(aw.z, h2.y, acc.y); acc.y = fmaf(aw.w, h3.y, acc.y);
      acc.z = fmaf(aw.x, h0.z, acc.z); acc.z = fmaf(aw.y, h1.z, acc.z);
      acc.z = fmaf(aw.z, h2.z, acc.z); acc.z = fmaf(aw.w, h3.z, acc.z);
      acc.w = fmaf(aw.x, h0.w, acc.w); acc.w = fmaf(aw.y, h1.w, acc.w);
      acc.w = fmaf(aw.z, h2.w, acc.w); acc.w = fmaf(aw.w, h3.w, acc.w);
    }
    float o[4] = {acc.x, acc.y, acc.z, acc.w};
    ushort4 r;
    ushort* rp = (ushort*)&r;
#pragma unroll
    for (int j = 0; j < 4; ++j) {
      int dd = d + j;
      float val = o[j] * 0.25f + bg[dd];
      float sc = bng[dd] / sqrtf(bng[3 * HD + dd] + BN_EPS);
      val = (val - bng[2 * HD + dd]) * sc + bng[HD + dd];
      val = 0.5f * val * (1.f + erff(val * 0.7071067811865475f));
      rp[j] = f2b(val);
    }
    *(ushort4*)&gb[(size_t)bn * HD + d] = r;
  }
}

// ---------------------------------------------------------------- fc2 via bf16 MFMA + BN + residual + fused transpose-out
__global__ __launch_bounds__(256) void k_fc2_mfma(
    const ushort* __restrict__ gb, const ushort* __restrict__ W2b,
    const float* __restrict__ b2, const float* __restrict__ bn2,
    const float* __restrict__ x, float* __restrict__ out) {
  int r0 = blockIdx.x * 64;           // global row (b*NN + n)
  int c0 = blockIdx.y * 64;           // col (c)
  int b = r0 >> 10, n0 = r0 & 1023;
  __shared__ ushort smem[2 * 64 * 72];   // reused as fp32 Ct[64][68]
  ushort* Al = smem;
  ushort* Bl = smem + 64 * 72;
  int t = threadIdx.x;
  int w = t >> 6, l = t & 63;
  int wr = w >> 1, wc = w & 1;
  f32x4 acc[2][2];
#pragma unroll
  for (int mt = 0; mt < 2; ++mt)
#pragma unroll
    for (int nt = 0; nt < 2; ++nt) acc[mt][nt] = {0.f, 0.f, 0.f, 0.f};
  for (int k0 = 0; k0 < HD; k0 += 64) {
    __syncthreads();
#pragma unroll
    for (int i = 0; i < 2; ++i) {
      int u = i * 256 + t;
      int r = u >> 3, ko = (u & 7) * 8;
      *(int4*)&Al[r * 72 + ko] = *(const int4*)&gb[(size_t)(r0 + r) * HD + k0 + ko];
      *(int4*)&Bl[r * 72 + ko] = *(const int4*)&W2b[(size_t)(c0 + r) * HD + k0 + ko];
    }
    __syncthreads();
#pragma unroll
    for (int ks = 0; ks < 2; ++ks) {
      bf16x8 af[2], bfr[2];
#pragma unroll
      for (int mt = 0; mt < 2; ++mt)
        af[mt] = *(const bf16x8*)&Al[(wr * 32 + mt * 16 + (l & 15)) * 72 + ks * 32 + (l >> 4) * 8];
#pragma unroll
      for (int nt = 0; nt < 2; ++nt)
        bfr[nt] = *(const bf16x8*)&Bl[(wc * 32 + nt * 16 + (l & 15)) * 72 + ks * 32 + (l >> 4) * 8];
#pragma unroll
      for (int mt = 0; mt < 2; ++mt)
#pragma unroll
        for (int nt = 0; nt < 2; ++nt)
          acc[mt][nt] = __builtin_amdgcn_mfma_f32_16x16x32_bf16(
              af[mt], bfr[nt], acc[mt][nt], 0, 0, 0);
    }
  }
  __syncthreads();
  float* ct = (float*)smem;              // [64][68]
  int col_l = l & 15, rg = l >> 4;
#pragma unroll
  for (int mt = 0; mt < 2; ++mt)
#pragma unroll
    for (int nt = 0; nt < 2; ++nt) {
      int cl = wc * 32 + nt * 16 + col_l;
      int nl = wr * 32 + mt * 16 + rg * 4;
      float4 v = {acc[mt][nt][0], acc[mt][nt][1], acc[mt][nt][2], acc[mt][nt][3]};
      *(float4*)&ct[cl * 68 + nl] = v;
    }
  __syncthreads();
#pragma unroll
  for (int i = 0; i < 4; ++i) {
    int u = i * 256 + t;
    int cl = u >> 4, q = u & 15;
    float4 v = *(const float4*)&ct[cl * 68 + q * 4];
    int c = c0 + cl;
    float s  = bn2[c] / sqrtf(bn2[3 * Cc + c] + BN_EPS);
    float mm = bn2[2 * Cc + c];
    float be = bn2[Cc + c];
    float bias = b2[c];
    size_t base = ((size_t)b * Cc + c) * NN + n0 + q * 4;
    float4 res = *(const float4*)&x[base];
    float4 o;
    o.x = (v.x + bias - mm) * s + be + res.x;
    o.y = (v.y + bias - mm) * s + be + res.y;
    o.z = (v.z + bias - mm) * s + be + res.z;
    o.w = (v.w + bias - mm) * s + be + res.w;
    *(float4*)&out[base] = o;
  }
}

extern "C" void kernel_launch(void* const* d_in, const int* in_sizes, int n_in,
                              void* d_out, int out_size, void* d_ws, size_t ws_size,
                              hipStream_t stream) {
  const float* x       = (const float*)d_in[0];
  const float* W1      = (const float*)d_in[1];
  const float* b1      = (const float*)d_in[2];
  const float* bn1     = (const float*)d_in[3];
  const float* Wg      = (const float*)d_in[4];
  const float* att_src = (const float*)d_in[5];
  const float* att_dst = (const float*)d_in[6];
  const float* bg      = (const float*)d_in[7];
  const float* bng     = (const float*)d_in[8];
  const float* W2      = (const float*)d_in[9];
  const float* b2      = (const float*)d_in[10];
  const float* bn2     = (const float*)d_in[11];
  float* out = (float*)d_out;

  // workspace layout
  float* ws    = (float*)d_ws;
  float* y     = ws;                         // 786432
  float* sq    = y + 786432;                 // 4096
  float* asrc  = sq + 4096;                  // 16384
  float* adst  = asrc + 16384;               // 16384
  float* dist  = adst + 16384;               // 4194304
  int*   idx   = (int*)(dist + 4194304);     // 65536
  float* yT    = dist + 4194304 + 65536;     // 786432
  float* W1T   = yT + 786432;                // 36864
  float* Asml  = W1T + 36864;                // 1536
  ushort* yb   = (ushort*)(Asml + 1536);     // 786432 u
  ushort* WgTb = yb + 786432;                // 294912 u
  ushort* hb   = WgTb + 294912;              // 6291456 u
  ushort* gb   = hb + 6291456;               // 1572864 u
  ushort* W2b  = gb + 1572864;               // 73728 u

  k_prep<<<402, 256, 0, stream>>>(W1, W2, Wg, att_src, att_dst, W1T, W2b, WgTb, Asml);
  k_fc1<<<dim3(16, 3, 4), 256, 0, stream>>>(x, W1T, b1, bn1, y, yb, yT);
  k_sqatt<<<Bb * NN, 64, 0, stream>>>(y, Asml, sq, asrc, adst);
  k_hgemm_mfma<<<dim3(32, 12), 256, 0, stream>>>(yb, WgTb, hb);
  k_dist<<<dim3(16, 8, 4), 256, 0, stream>>>(yT, sq, dist);
  k_topk<<<Bb * NN, 64, 0, stream>>>(dist, idx);
  k_gat<<<Bb * NN, 128, 0, stream>>>(hb, asrc, adst, idx, bg, bng, gb);
  k_fc2_mfma<<<dim3(64, 3), 256, 0, stream>>>(gb, W2b, b2, bn2, x, out);
}

// Round 16
// 133.657 us; speedup vs baseline: 1.0593x; 1.0593x over previous
//
#include <hip/hip_runtime.h>
#include <math.h>

#define Bb 4
#define Cc 192
#define NN 1024
#define HD 384
#define NH 4
#define FF 1536   // NH*HD
#define KN 16
#define BN_EPS 1e-5f

typedef __attribute__((ext_vector_type(8))) short bf16x8;
typedef __attribute__((ext_vector_type(4))) float f32x4;

__device__ inline float b2f(ushort u) {
  return __uint_as_float(((unsigned)u) << 16);
}
__device__ inline ushort f2b(float f) {
  unsigned v = __float_as_uint(f);
  return (ushort)((v + 0x7fffu + ((v >> 16) & 1u)) >> 16);
}

// one row of register-tile FMAs: acc.{x,y,z,w} += av * b.{x,y,z,w}
#define FMA_ROW(ACC, AV, B) \
  ACC.x = fmaf(AV, B.x, ACC.x); ACC.y = fmaf(AV, B.y, ACC.y); \
  ACC.z = fmaf(AV, B.z, ACC.z); ACC.w = fmaf(AV, B.w, ACC.w);

// ---------------------------------------------------------------- prep:
// W1T fp32 transpose (36 blk), W2b bf16 convert row-major (72 blk),
// WgTb bf16 transpose (288 blk). Total 396 blocks.
__global__ __launch_bounds__(256) void k_prep(
    const float* __restrict__ W1, const float* __restrict__ W2,
    const float* __restrict__ Wg, float* __restrict__ W1T,
    ushort* __restrict__ W2b, ushort* __restrict__ WgTb) {
  __shared__ float tile[32][33];
  int id = blockIdx.x;
  int t = threadIdx.x;
  if (id < 36 || id >= 108) {
    const float* in; int R, C, cx, cy;
    float* outf = nullptr; ushort* outb = nullptr;
    if (id < 36) { in = W1; R = Cc; C = Cc; cx = id % 6; cy = id / 6; outf = W1T; }
    else { int q = id - 108; in = Wg; R = Cc; C = FF; cx = q % 48; cy = q / 48; outb = WgTb; }
    int c0 = cx * 32, r0 = cy * 32;
    int tx = t & 31, ty = t >> 5;
#pragma unroll
    for (int i = 0; i < 4; ++i) {
      int r = ty + i * 8;
      tile[r][tx] = in[(size_t)(r0 + r) * C + c0 + tx];
    }
    __syncthreads();
#pragma unroll
    for (int i = 0; i < 4; ++i) {
      int r = ty + i * 8;
      float v = tile[tx][r];
      if (outf) outf[(size_t)(c0 + r) * R + r0 + tx] = v;
      else      outb[(size_t)(c0 + r) * R + r0 + tx] = f2b(v);
    }
  } else {                             // W2 bf16 convert (row-major kept)
    int base = (id - 36) * 1024 + t * 4;
    float4 v = *(const float4*)&W2[base];
    ushort4 o = {f2b(v.x), f2b(v.y), f2b(v.z), f2b(v.w)};
    *(ushort4*)&W2b[base] = o;
  }
}

// ---------------------------------------------------------------- fc1 + BN (bit-frozen; emits y fp32, yb bf16, yT fp32)
// yT write fused here (replaces k_tr): same o bits staged via padded LDS tile.
__global__ __launch_bounds__(256) void k_fc1(
    const float* __restrict__ x, const float* __restrict__ W1T,
    const float* __restrict__ b1, const float* __restrict__ bn1,
    float* __restrict__ y, ushort* __restrict__ yb,
    float* __restrict__ yT) {
  int nt = blockIdx.x, ct = blockIdx.y, b = blockIdx.z;
  int n0 = nt * 64, ct64 = ct * 64;
  __shared__ float As[64][64];
  __shared__ float Bs[64][64];
  __shared__ float ctile[64][68];   // [c][n], 68 stride: 16B-aligned rows
  int t = threadIdx.x;
  int tx = t & 15, ty = t >> 4;
  float4 acc[4];
#pragma unroll
  for (int i = 0; i < 4; ++i) acc[i] = {0.f, 0.f, 0.f, 0.f};
  for (int k0 = 0; k0 < Cc; k0 += 64) {
    __syncthreads();
#pragma unroll
    for (int i = 0; i < 4; ++i) {
      int fi = i * 256 + t;
      int r = fi >> 4, q = fi & 15;
      *(float4*)&As[r][q * 4] =
          *(const float4*)&x[((size_t)b * Cc + k0 + r) * NN + n0 + q * 4];
      *(float4*)&Bs[r][q * 4] =
          *(const float4*)&W1T[(size_t)(k0 + r) * Cc + ct64 + q * 4];
    }
    __syncthreads();
#pragma unroll 8
    for (int k = 0; k < 64; ++k) {
      float4 a = *(const float4*)&As[k][ty * 4];
      float4 bv = *(const float4*)&Bs[k][tx * 4];
      FMA_ROW(acc[0], a.x, bv)
      FMA_ROW(acc[1], a.y, bv)
      FMA_ROW(acc[2], a.z, bv)
      FMA_ROW(acc[3], a.w, bv)
    }
  }
  float s[4], mm[4], be[4], bias[4];
#pragma unroll
  for (int jj = 0; jj < 4; ++jj) {
    int c = ct64 + tx * 4 + jj;
    s[jj]    = bn1[c] / sqrtf(bn1[3 * Cc + c] + BN_EPS);
    mm[jj]   = bn1[2 * Cc + c];
    be[jj]   = bn1[Cc + c];
    bias[jj] = b1[c];
  }
  float accm[4][4] = {
      {acc[0].x, acc[0].y, acc[0].z, acc[0].w},
      {acc[1].x, acc[1].y, acc[1].z, acc[1].w},
      {acc[2].x, acc[2].y, acc[2].z, acc[2].w},
      {acc[3].x, acc[3].y, acc[3].z, acc[3].w}};
#pragma unroll
  for (int ii = 0; ii < 4; ++ii) {
    int n = n0 + ty * 4 + ii;
    float4 o;
    o.x = (accm[ii][0] + bias[0] - mm[0]) * s[0] + be[0];
    o.y = (accm[ii][1] + bias[1] - mm[1]) * s[1] + be[1];
    o.z = (accm[ii][2] + bias[2] - mm[2]) * s[2] + be[2];
    o.w = (accm[ii][3] + bias[3] - mm[3]) * s[3] + be[3];
    *(float4*)&y[((size_t)b * NN + n) * Cc + ct64 + tx * 4] = o;
    ushort4 ob = {f2b(o.x), f2b(o.y), f2b(o.z), f2b(o.w)};
    *(ushort4*)&yb[((size_t)b * NN + n) * Cc + ct64 + tx * 4] = ob;
    ctile[tx * 4 + 0][ty * 4 + ii] = o.x;
    ctile[tx * 4 + 1][ty * 4 + ii] = o.y;
    ctile[tx * 4 + 2][ty * 4 + ii] = o.z;
    ctile[tx * 4 + 3][ty * 4 + ii] = o.w;
  }
  __syncthreads();
#pragma unroll
  for (int i = 0; i < 4; ++i) {        // 64 c-rows x 16 float4 n-units
    int u = i * 256 + t;
    int cl = u >> 4, q = u & 15;
    float4 v = *(const float4*)&ctile[cl][q * 4];
    *(float4*)&yT[((size_t)b * Cc + ct64 + cl) * NN + n0 + q * 4] = v;
  }
}

// ---------------------------------------------------------------- row sums of y^2 (bit-frozen)
__global__ __launch_bounds__(64) void k_sq(const float* __restrict__ y,
                                           float* __restrict__ sq) {
  int bn = blockIdx.x;
  int lane = threadIdx.x;
  const float* yp = y + (size_t)bn * Cc;
  float s = 0.f;
  for (int k = lane; k < Cc; k += 64) { float v = yp[k]; s = fmaf(v, v, s); }
#pragma unroll
  for (int off = 32; off; off >>= 1) s += __shfl_down(s, off);
  if (lane == 0) sq[bn] = s;
}

// ---------------------------------------------------------------- h = y @ Wg via bf16 MFMA -> hb
__global__ __launch_bounds__(256) void k_hgemm_mfma(
    const ushort* __restrict__ yb, const ushort* __restrict__ WgTb,
    ushort* __restrict__ hb) {
  int r0 = blockIdx.x * 128, c0 = blockIdx.y * 128;
  __shared__ ushort Al[128][72];
  __shared__ ushort Bl[128][72];
  int t = threadIdx.x;
  int w = t >> 6, l = t & 63;
  int wr = w >> 1, wc = w & 1;
  f32x4 acc[4][4];
#pragma unroll
  for (int mt = 0; mt < 4; ++mt)
#pragma unroll
    for (int nt = 0; nt < 4; ++nt) acc[mt][nt] = {0.f, 0.f, 0.f, 0.f};
  for (int k0 = 0; k0 < Cc; k0 += 64) {
    __syncthreads();
#pragma unroll
    for (int i = 0; i < 4; ++i) {
      int u = i * 256 + t;
      int r = u >> 3, ko = (u & 7) * 8;
      *(int4*)&Al[r][ko] = *(const int4*)&yb[(size_t)(r0 + r) * Cc + k0 + ko];
      *(int4*)&Bl[r][ko] = *(const int4*)&WgTb[(size_t)(c0 + r) * Cc + k0 + ko];
    }
    __syncthreads();
#pragma unroll
    for (int ks = 0; ks < 2; ++ks) {
      bf16x8 af[4], bfr[4];
#pragma unroll
      for (int mt = 0; mt < 4; ++mt)
        af[mt] = *(const bf16x8*)&Al[wr * 64 + mt * 16 + (l & 15)][ks * 32 + (l >> 4) * 8];
#pragma unroll
      for (int nt = 0; nt < 4; ++nt)
        bfr[nt] = *(const bf16x8*)&Bl[wc * 64 + nt * 16 + (l & 15)][ks * 32 + (l >> 4) * 8];
#pragma unroll
      for (int mt = 0; mt < 4; ++mt)
#pragma unroll
        for (int nt = 0; nt < 4; ++nt)
          acc[mt][nt] = __builtin_amdgcn_mfma_f32_16x16x32_bf16(
              af[mt], bfr[nt], acc[mt][nt], 0, 0, 0);
    }
  }
  int col_l = l & 15, rg = l >> 4;
#pragma unroll
  for (int mt = 0; mt < 4; ++mt)
#pragma unroll
    for (int nt = 0; nt < 4; ++nt) {
      int col = c0 + wc * 64 + nt * 16 + col_l;
#pragma unroll
      for (int j = 0; j < 4; ++j) {
        int row = r0 + wr * 64 + mt * 16 + rg * 4 + j;
        hb[(size_t)row * FF + col] = f2b(acc[mt][nt][j]);
      }
    }
}

// ---------------------------------------------------------------- a_src / a_dst from bf16 h
__global__ __launch_bounds__(256) void k_attn_coef(
    const ushort* __restrict__ hb, const float* __restrict__ att_src,
    const float* __restrict__ att_dst, float* __restrict__ asrc,
    float* __restrict__ adst) {
  int bn = blockIdx.x;
  int head = threadIdx.x / 64, lane = threadIdx.x % 64;
  const ushort* hp = hb + (size_t)bn * FF + head * HD;
  const float* as = att_src + head * HD;
  const float* ad = att_dst + head * HD;
  float s1 = 0.f, s2 = 0.f;
  for (int d = lane; d < HD; d += 64) {
    float v = b2f(hp[d]);
    s1 = fmaf(v, as[d], s1);
    s2 = fmaf(v, ad[d], s2);
  }
#pragma unroll
  for (int off = 32; off; off >>= 1) {
    s1 += __shfl_down(s1, off);
    s2 += __shfl_down(s2, off);
  }
  if (lane == 0) {
    asrc[bn * NH + head] = s1;
    adst[bn * NH + head] = s2;
  }
}

// ---------------------------------------------------------------- pairwise distances (bit-frozen; 128x64, 8x4/thread)
__global__ __launch_bounds__(256) void k_dist(const float* __restrict__ yT,
                                              const float* __restrict__ sq,
                                              float* __restrict__ dist) {
  int b = blockIdx.z;
  int n0 = blockIdx.y * 128, m0 = blockIdx.x * 64;
  __shared__ float As[64][128];
  __shared__ float Bs[64][64];
  const float* ytb = yT + (size_t)b * Cc * NN;
  int t = threadIdx.x;
  int tx = t & 15, ty = t >> 4;
  float4 acc[8];
#pragma unroll
  for (int i = 0; i < 8; ++i) acc[i] = {0.f, 0.f, 0.f, 0.f};
  for (int k0 = 0; k0 < Cc; k0 += 64) {
    __syncthreads();
#pragma unroll
    for (int i = 0; i < 8; ++i) {
      int fi = i * 256 + t;
      int kk = fi >> 5, n4 = fi & 31;
      *(float4*)&As[kk][n4 * 4] =
          *(const float4*)&ytb[(size_t)(k0 + kk) * NN + n0 + n4 * 4];
    }
#pragma unroll
    for (int i = 0; i < 4; ++i) {
      int fi = i * 256 + t;
      int kk = fi >> 4, m4 = fi & 15;
      *(float4*)&Bs[kk][m4 * 4] =
          *(const float4*)&ytb[(size_t)(k0 + kk) * NN + m0 + m4 * 4];
    }
    __syncthreads();
#pragma unroll 8
    for (int k = 0; k < 64; ++k) {
      float4 a0 = *(const float4*)&As[k][ty * 4];
      float4 a1 = *(const float4*)&As[k][64 + ty * 4];
      float4 b4 = *(const float4*)&Bs[k][tx * 4];
      FMA_ROW(acc[0], a0.x, b4)
      FMA_ROW(acc[1], a0.y, b4)
      FMA_ROW(acc[2], a0.z, b4)
      FMA_ROW(acc[3], a0.w, b4)
      FMA_ROW(acc[4], a1.x, b4)
      FMA_ROW(acc[5], a1.y, b4)
      FMA_ROW(acc[6], a1.z, b4)
      FMA_ROW(acc[7], a1.w, b4)
    }
  }
#pragma unroll
  for (int ii = 0; ii < 8; ++ii) {
    int n = n0 + ((ii < 4) ? (ty * 4 + ii) : (64 + ty * 4 + ii - 4));
    float sn = sq[b * NN + n];
    int mbase = m0 + tx * 4;
    float av[4] = {acc[ii].x, acc[ii].y, acc[ii].z, acc[ii].w};
    float4 o;
    o.x = sn + sq[b * NN + mbase + 0] - 2.f * av[0];
    o.y = sn + sq[b * NN + mbase + 1] - 2.f * av[1];
    o.z = sn + sq[b * NN + mbase + 2] - 2.f * av[2];
    o.w = sn + sq[b * NN + mbase + 3] - 2.f * av[3];
    *(float4*)&dist[((size_t)b * NN + n) * NN + mbase] = o;
  }
}

// ---------------------------------------------------------------- top-16 smallest per row (bit-frozen; single-wave)
__global__ __launch_bounds__(64) void k_topk(const float* __restrict__ dist,
                                             int* __restrict__ idx) {
  int bn = blockIdx.x;
  int lane = threadIdx.x;
  const float4* dp = (const float4*)(dist + (size_t)bn * NN);
  float dv[16];
#pragma unroll
  for (int q = 0; q < 4; ++q) {
    float4 v = dp[lane + 64 * q];
    dv[q * 4 + 0] = v.x; dv[q * 4 + 1] = v.y;
    dv[q * 4 + 2] = v.z; dv[q * 4 + 3] = v.w;
  }
  for (int sel = 0; sel < KN; ++sel) {
    float bv = INFINITY;
    int bi = 0x7fffffff;
#pragma unroll
    for (int q = 0; q < 4; ++q)
#pragma unroll
      for (int j = 0; j < 4; ++j) {
        int m = (lane + 64 * q) * 4 + j;
        float v = dv[q * 4 + j];
        if (v < bv || (v == bv && m < bi)) { bv = v; bi = m; }
      }
#pragma unroll
    for (int off = 32; off; off >>= 1) {
      float ov = __shfl_xor(bv, off);
      int oi   = __shfl_xor(bi, off);
      if (ov < bv || (ov == bv && oi < bi)) { bv = ov; bi = oi; }
    }
    if (lane == 0) idx[bn * KN + sel] = bi;
#pragma unroll
    for (int q = 0; q < 4; ++q)
#pragma unroll
      for (int j = 0; j < 4; ++j)
        if ((lane + 64 * q) * 4 + j == bi) dv[q * 4 + j] = INFINITY;
  }
}

// ---------------------------------------------------------------- GAT aggregate + BN + GELU -> gb (bf16)
__global__ __launch_bounds__(128, 4) void k_gat(
    const ushort* __restrict__ hb, const float* __restrict__ asrc,
    const float* __restrict__ adst, const int* __restrict__ idx,
    const float* __restrict__ bg, const float* __restrict__ bng,
    ushort* __restrict__ gb) {
  int bid = blockIdx.x;
  int bn = (bid & 7) * (Bb * NN / 8) + (bid >> 3);   // bijective XCD swizzle
  int b = bn / NN;
  __shared__ int nb[KN];
  __shared__ float attn[KN][NH];
  int t = threadIdx.x;
  if (t < KN) nb[t] = idx[bn * KN + t];
  __syncthreads();
  if (t < KN * NH) {
    int k = t % KN, hd = t / KN;
    float e = asrc[((size_t)b * NN + nb[k]) * NH + hd] +
              adst[(size_t)bn * NH + hd];
    e = (e >= 0.f) ? e : 0.2f * e;
    attn[k][hd] = e;
  }
  __syncthreads();
  if (t < NH) {
    float mx = -INFINITY;
    for (int k = 0; k < KN; ++k) mx = fmaxf(mx, attn[k][t]);
    float s = 0.f;
    for (int k = 0; k < KN; ++k) {
      float ev = expf(attn[k][t] - mx);
      attn[k][t] = ev;
      s += ev;
    }
    float inv = 1.f / s;
    for (int k = 0; k < KN; ++k) attn[k][t] *= inv;
  }
  __syncthreads();
  if (t < 96) {
    int d = t * 4;
    float4 acc = {0.f, 0.f, 0.f, 0.f};
#pragma unroll 4
    for (int k = 0; k < KN; ++k) {
      const ushort* hp = hb + ((size_t)b * NN + nb[k]) * FF + d;
      float4 aw = *(const float4*)&attn[k][0];
      ushort4 u0 = *(const ushort4*)&hp[0];
      ushort4 u1 = *(const ushort4*)&hp[HD];
      ushort4 u2 = *(const ushort4*)&hp[2 * HD];
      ushort4 u3 = *(const ushort4*)&hp[3 * HD];
      float4 h0 = {b2f(u0.x), b2f(u0.y), b2f(u0.z), b2f(u0.w)};
      float4 h1 = {b2f(u1.x), b2f(u1.y), b2f(u1.z), b2f(u1.w)};
      float4 h2 = {b2f(u2.x), b2f(u2.y), b2f(u2.z), b2f(u2.w)};
      float4 h3 = {b2f(u3.x), b2f(u3.y), b2f(u3.z), b2f(u3.w)};
      acc.x = fmaf(aw.x, h0.x, acc.x); acc.x = fmaf(aw.y, h1.x, acc.x);
      acc.x = fmaf(aw.z, h2.x, acc.x); acc.x = fmaf(aw.w, h3.x, acc.x);
      acc.y = fmaf(aw.x, h0.y, acc.y); acc.y = fmaf(aw.y, h1.y, acc.y);
      acc.y = fmaf(aw.z, h2.y, acc.y); acc.y = fmaf(aw.w, h3.y, acc.y);
      acc.z = fmaf(aw.x, h0.z, acc.z); acc.z = fmaf(aw.y, h1.z, acc.z);
      acc.z = fmaf(aw.z, h2.z, acc.z); acc.z = fmaf(aw.w, h3.z, acc.z);
      acc.w = fmaf(aw.x, h0.w, acc.w); acc.w = fmaf(aw.y, h1.w, acc.w);
      acc.w = fmaf(aw.z, h2.w, acc.w); acc.w = fmaf(aw.w, h3.w, acc.w);
    }
    float o[4] = {acc.x, acc.y, acc.z, acc.w};
    ushort4 r;
    ushort* rp = (ushort*)&r;
#pragma unroll
    for (int j = 0; j < 4; ++j) {
      int dd = d + j;
      float val = o[j] * 0.25f + bg[dd];
      float sc = bng[dd] / sqrtf(bng[3 * HD + dd] + BN_EPS);
      val = (val - bng[2 * HD + dd]) * sc + bng[HD + dd];
      val = 0.5f * val * (1.f + erff(val * 0.7071067811865475f));
      rp[j] = f2b(val);
    }
    *(ushort4*)&gb[(size_t)bn * HD + d] = r;
  }
}

// ---------------------------------------------------------------- fc2 via bf16 MFMA + BN + residual + fused transpose-out
__global__ __launch_bounds__(256) void k_fc2_mfma(
    const ushort* __restrict__ gb, const ushort* __restrict__ W2b,
    const float* __restrict__ b2, const float* __restrict__ bn2,
    const float* __restrict__ x, float* __restrict__ out) {
  int r0 = blockIdx.x * 64;           // global row (b*NN + n)
  int c0 = blockIdx.y * 64;           // col (c)
  int b = r0 >> 10, n0 = r0 & 1023;
  __shared__ ushort smem[2 * 64 * 72];   // reused as fp32 Ct[64][68]
  ushort* Al = smem;
  ushort* Bl = smem + 64 * 72;
  int t = threadIdx.x;
  int w = t >> 6, l = t & 63;
  int wr = w >> 1, wc = w & 1;
  f32x4 acc[2][2];
#pragma unroll
  for (int mt = 0; mt < 2; ++mt)
#pragma unroll
    for (int nt = 0; nt < 2; ++nt) acc[mt][nt] = {0.f, 0.f, 0.f, 0.f};
  for (int k0 = 0; k0 < HD; k0 += 64) {
    __syncthreads();
#pragma unroll
    for (int i = 0; i < 2; ++i) {
      int u = i * 256 + t;
      int r = u >> 3, ko = (u & 7) * 8;
      *(int4*)&Al[r * 72 + ko] = *(const int4*)&gb[(size_t)(r0 + r) * HD + k0 + ko];
      *(int4*)&Bl[r * 72 + ko] = *(const int4*)&W2b[(size_t)(c0 + r) * HD + k0 + ko];
    }
    __syncthreads();
#pragma unroll
    for (int ks = 0; ks < 2; ++ks) {
      bf16x8 af[2], bfr[2];
#pragma unroll
      for (int mt = 0; mt < 2; ++mt)
        af[mt] = *(const bf16x8*)&Al[(wr * 32 + mt * 16 + (l & 15)) * 72 + ks * 32 + (l >> 4) * 8];
#pragma unroll
      for (int nt = 0; nt < 2; ++nt)
        bfr[nt] = *(const bf16x8*)&Bl[(wc * 32 + nt * 16 + (l & 15)) * 72 + ks * 32 + (l >> 4) * 8];
#pragma unroll
      for (int mt = 0; mt < 2; ++mt)
#pragma unroll
        for (int nt = 0; nt < 2; ++nt)
          acc[mt][nt] = __builtin_amdgcn_mfma_f32_16x16x32_bf16(
              af[mt], bfr[nt], acc[mt][nt], 0, 0, 0);
    }
  }
  __syncthreads();
  float* ct = (float*)smem;              // [64][68]
  int col_l = l & 15, rg = l >> 4;
#pragma unroll
  for (int mt = 0; mt < 2; ++mt)
#pragma unroll
    for (int nt = 0; nt < 2; ++nt) {
      int cl = wc * 32 + nt * 16 + col_l;
      int nl = wr * 32 + mt * 16 + rg * 4;
      float4 v = {acc[mt][nt][0], acc[mt][nt][1], acc[mt][nt][2], acc[mt][nt][3]};
      *(float4*)&ct[cl * 68 + nl] = v;
    }
  __syncthreads();
#pragma unroll
  for (int i = 0; i < 4; ++i) {
    int u = i * 256 + t;
    int cl = u >> 4, q = u & 15;
    float4 v = *(const float4*)&ct[cl * 68 + q * 4];
    int c = c0 + cl;
    float s  = bn2[c] / sqrtf(bn2[3 * Cc + c] + BN_EPS);
    float mm = bn2[2 * Cc + c];
    float be = bn2[Cc + c];
    float bias = b2[c];
    size_t base = ((size_t)b * Cc + c) * NN + n0 + q * 4;
    float4 res = *(const float4*)&x[base];
    float4 o;
    o.x = (v.x + bias - mm) * s + be + res.x;
    o.y = (v.y + bias - mm) * s + be + res.y;
    o.z = (v.z + bias - mm) * s + be + res.z;
    o.w = (v.w + bias - mm) * s + be + res.w;
    *(float4*)&out[base] = o;
  }
}

extern "C" void kernel_launch(void* const* d_in, const int* in_sizes, int n_in,
                              void* d_out, int out_size, void* d_ws, size_t ws_size,
                              hipStream_t stream) {
  const float* x       = (const float*)d_in[0];
  const float* W1      = (const float*)d_in[1];
  const float* b1      = (const float*)d_in[2];
  const float* bn1     = (const float*)d_in[3];
  const float* Wg      = (const float*)d_in[4];
  const float* att_src = (const float*)d_in[5];
  const float* att_dst = (const float*)d_in[6];
  const float* bg      = (const float*)d_in[7];
  const float* bng     = (const float*)d_in[8];
  const float* W2      = (const float*)d_in[9];
  const float* b2      = (const float*)d_in[10];
  const float* bn2     = (const float*)d_in[11];
  float* out = (float*)d_out;

  // workspace layout
  float* ws    = (float*)d_ws;
  float* y     = ws;                         // 786432
  float* sq    = y + 786432;                 // 4096
  float* asrc  = sq + 4096;                  // 16384
  float* adst  = asrc + 16384;               // 16384
  float* dist  = adst + 16384;               // 4194304
  int*   idx   = (int*)(dist + 4194304);     // 65536
  float* yT    = dist + 4194304 + 65536;     // 786432
  float* W1T   = yT + 786432;                // 36864
  ushort* yb   = (ushort*)(W1T + 36864);     // 786432 u
  ushort* WgTb = yb + 786432;                // 294912 u
  ushort* hb   = WgTb + 294912;              // 6291456 u
  ushort* gb   = hb + 6291456;               // 1572864 u
  ushort* W2b  = gb + 1572864;               // 73728 u

  k_prep<<<396, 256, 0, stream>>>(W1, W2, Wg, W1T, W2b, WgTb);
  k_fc1<<<dim3(16, 3, 4), 256, 0, stream>>>(x, W1T, b1, bn1, y, yb, yT);
  k_sq<<<Bb * NN, 64, 0, stream>>>(y, sq);
  k_hgemm_mfma<<<dim3(32, 12), 256, 0, stream>>>(yb, WgTb, hb);
  k_attn_coef<<<Bb * NN, 256, 0, stream>>>(hb, att_src, att_dst, asrc, adst);
  k_dist<<<dim3(16, 8, 4), 256, 0, stream>>>(yT, sq, dist);
  k_topk<<<Bb * NN, 64, 0, stream>>>(dist, idx);
  k_gat<<<Bb * NN, 128, 0, stream>>>(hb, asrc, adst, idx, bg, bng, gb);
  k_fc2_mfma<<<dim3(64, 3), 256, 0, stream>>>(gb, W2b, b2, bn2, x, out);
}